// Round 7
// baseline (268.903 us; speedup 1.0000x reference)
//
#include <hip/hip_runtime.h>

// One wavefront = one 9-qubit patch circuit; ZERO block-level barriers in the
// main path (per-wave LDS tables, wave-internal lgkmcnt ordering). FC fused
// via last-block-done (1 atomicAdd/block on a memset-zeroed counter).
//
// Qubit -> bit remap:
//   qubit 0 -> reg bit 0 (R0)  qubit 3 -> reg bit 1 (R1)  qubit 6 -> reg bit 2 (R2)
//   qubit 1 -> lane bit 0      qubit 2 -> lane bit 1      qubit 4 -> lane bit 2
//   qubit 5 -> lane bit 3      qubit 7 -> lane bit 4      qubit 8 -> lane bit 5
//
// Pipeline (verified math from R6 + two new folds):
//   enc RY + conv1 RY -> per-qubit (c,s);  conv1 RZ folds into tau_q(b)
//   ring CNOT eliminated analytically (GF(2)-linear) -> product state
//     p0(R0) x p1(R1) x p2(R2) per lane
//   pool1 -> per-lane RX on each factor (LUT by 2 lane bits)
// * conv2's RY/RZ on q0,q3,q6 applied AT FACTOR LEVEL (2-vectors), then expand
// * RY(w34)RY(w36) and RY(w35)RY(w37) folded (commute, angles add)
//   -> only 10 parametrized full-state gates + 4 free CX permutations
//   measure qubit0; ez = 2*P(even)-1
//
// Lessons kept: no per-patch atomics (R2), 1 patch/wave (R4), no block-shared
// M / no rendezvous (R5/R6). The 256MB d_ws poison fill (~40us) is fixed.

__device__ __forceinline__ float shx(float v, int m) { return __shfl_xor(v, m, 64); }

__device__ __forceinline__ float2 cmul(float2 a, float2 b) {
  return make_float2(a.x * b.x - a.y * b.y, a.x * b.y + a.y * b.x);
}

// ---- full-state reg-qubit gates ----
template <int TM> __device__ __forceinline__
void ry_r(float (&re)[8], float (&im)[8], float c, float s) {
#pragma unroll
  for (int r0 = 0; r0 < 8; ++r0) if (!(r0 & TM)) {
    const int r1 = r0 | TM;
    float a = re[r0], bb = re[r1];
    re[r0] = c * a - s * bb; re[r1] = s * a + c * bb;
    a = im[r0]; bb = im[r1];
    im[r0] = c * a - s * bb; im[r1] = s * a + c * bb;
  }
}
template <int TM> __device__ __forceinline__
void rz_r(float (&re)[8], float (&im)[8], float c, float s) {
#pragma unroll
  for (int r = 0; r < 8; ++r) {
    const float sg = (r & TM) ? s : -s;
    const float a = re[r], bb = im[r];
    re[r] = c * a - sg * bb;
    im[r] = c * bb + sg * a;
  }
}
template <int CM, int TM> __device__ __forceinline__
void cx_rr(float (&re)[8], float (&im)[8]) {
#pragma unroll
  for (int r0 = 0; r0 < 8; ++r0) if ((r0 & CM) && !(r0 & TM)) {
    const int r1 = r0 | TM;
    float t = re[r0]; re[r0] = re[r1]; re[r1] = t;
    t = im[r0]; im[r0] = im[r1]; im[r1] = t;
  }
}
template <int CM, int TM> __device__ __forceinline__
void crx_rr(float (&re)[8], float (&im)[8], float co, float si) {
#pragma unroll
  for (int r0 = 0; r0 < 8; ++r0) if ((r0 & CM) && !(r0 & TM)) {
    const int r1 = r0 | TM;
    const float r0r = re[r0], r0i = im[r0], r1r = re[r1], r1i = im[r1];
    re[r0] = co * r0r + si * r1i; im[r0] = co * r0i - si * r1r;
    re[r1] = co * r1r + si * r0i; im[r1] = co * r1i - si * r0r;
  }
}

// ---- factor-level single-qubit gates on a complex 2-vector (A,B) ----
__device__ __forceinline__
void ry_f(float2& A, float2& B, float c, float s) {
  const float2 nA = make_float2(c * A.x - s * B.x, c * A.y - s * B.y);
  const float2 nB = make_float2(s * A.x + c * B.x, s * A.y + c * B.y);
  A = nA; B = nB;
}
__device__ __forceinline__
void rz_f(float2& A, float2& B, float c, float s) {
  A = make_float2(c * A.x + s * A.y, c * A.y - s * A.x);   // * e^{-i t/2}
  B = make_float2(c * B.x - s * B.y, c * B.y + s * B.x);   // * e^{+i t/2}
}
__device__ __forceinline__
void rx_f(float2& A, float2& B, float c, float s) {         // pool1 folded RX
  const float2 nA = make_float2(c * A.x + s * B.y, c * A.y - s * B.x);
  const float2 nB = make_float2(c * B.x + s * A.y, c * B.y - s * A.x);
  A = nA; B = nB;
}

__global__ __launch_bounds__(256) void qcnn_all(const float* __restrict__ x,
                                                const float* __restrict__ w,
                                                const float* __restrict__ fc_w,
                                                const float* __restrict__ fc_b,
                                                float* __restrict__ feats,
                                                unsigned int* __restrict__ counter,
                                                float* __restrict__ out,
                                                int nblk) {
  // per-wave LDS regions — no cross-wave sharing, no barriers needed
  __shared__ float4 tauT[4][9];    // qubit q -> (t0r, t0i, t1r, t1i)
  __shared__ float2 rxT[4][12];    // pool1 RX LUT [axis][2 control bits]
  __shared__ float2 gT[4][16];     // 16 folded gate params (cos, sin)

  const int tid = threadIdx.x;
  const int wv = tid >> 6, lane = tid & 63;
  const unsigned p = blockIdx.x * 4u + wv;           // patch id (grid exact)
  const unsigned b = p / 676u;
  const unsigned rem = p - b * 676u;
  const unsigned i = rem / 26u, j = rem - i * 26u;

  // ---- stage A: per-wave table build (lane roles; wave-internal ordering) ----
  if (lane < 9) {
    // encoding+conv1-RY sincos and conv1-RZ fold for qubit `lane`
    const int di = lane / 3, dj = lane - di * 3;
    const float xv = x[b * 784u + (i + di) * 28u + (j + dj)];
    const float ang = fmaf(xv, 3.14159265358979323846f, w[lane]) * 0.5f;
    float s, c; __sincosf(ang, &s, &c);
    float zs, zc; __sincosf(0.5f * w[9 + lane], &zs, &zc);
    tauT[wv][lane] = make_float4(c * zc, -c * zs, s * zc, s * zs);
  } else if (lane < 21) {
    const int k = lane - 9, a = k >> 2, cb = k & 3;
    float th = 0.0f;
    if (cb & 1) th += w[18 + 2 * a];
    if (cb & 2) th += w[19 + 2 * a];
    float s, c; __sincosf(0.5f * th, &s, &c);
    rxT[wv][k] = make_float2(c, s);
  } else if (lane < 37) {
    const int k = lane - 21;
    float th;
    if (k < 10)       th = w[24 + k];            // w24..w33
    else if (k == 10) th = w[34] + w[36];        // folded RY q0
    else if (k == 11) th = w[35] + w[37];        // folded RY q6
    else              th = w[26 + k];            // w38..w41
    float s, c; __sincosf(0.5f * th, &s, &c);
    gT[wv][k] = make_float2(c, s);
  }
  // (no __syncthreads: writes and reads are by the SAME wave — lgkmcnt orders)

  const int l0 = lane & 1, l1 = (lane >> 1) & 1, l2 = (lane >> 2) & 1;
  const int l3 = (lane >> 3) & 1, l4 = (lane >> 4) & 1, l5 = (lane >> 5) & 1;

  // tau from per-wave LDS (broadcast reads)
  float4 tq[9];
#pragma unroll
  for (int q = 0; q < 9; ++q) tq[q] = tauT[wv][q];
  auto tau = [&](int bit, int q) -> float2 {
    const float4 t = tq[q];
    return bit ? make_float2(t.z, t.w) : make_float2(t.x, t.y);
  };

  // post-ring product-state factors (derivation verified R6)
  const int a0 = l5, a1 = l0 ^ l5;
  float2 p00 = cmul(tau(a0, 0), tau(a1, 1));
  float2 p01 = cmul(tau(a0 ^ 1, 0), tau(a1 ^ 1, 1));
  float2 p10 = cmul(tau(l1, 3), tau(l2, 4));
  float2 p11 = cmul(tau(l1 ^ 1, 3), tau(l2 ^ 1, 4));
  float2 p20 = cmul(tau(l3, 6), tau(l4, 7));
  float2 p21 = cmul(tau(l3 ^ 1, 6), tau(l4 ^ 1, 7));
  const float2 T = cmul(cmul(tau(l0 ^ l1, 2), tau(l2 ^ l3, 5)), tau(l4 ^ l5, 8));
  p20 = cmul(p20, T);
  p21 = cmul(p21, T);

  // pool1: per-lane RX on each factor
  {
    const float2 x0 = rxT[wv][lane & 3];
    const float2 x1 = rxT[wv][4 + ((lane >> 2) & 3)];
    const float2 x2 = rxT[wv][8 + ((lane >> 4) & 3)];
    rx_f(p00, p01, x0.x, x0.y);
    rx_f(p10, p11, x1.x, x1.y);
    rx_f(p20, p21, x2.x, x2.y);
  }

  // conv2 single-qubit layer at FACTOR level (w24..w29)
  {
    const float2 g0 = gT[wv][0], g1 = gT[wv][1], g2 = gT[wv][2];
    const float2 g3 = gT[wv][3], g4 = gT[wv][4], g5 = gT[wv][5];
    ry_f(p00, p01, g0.x, g0.y);   // RY q0
    ry_f(p10, p11, g1.x, g1.y);   // RY q3
    ry_f(p20, p21, g2.x, g2.y);   // RY q6
    rz_f(p00, p01, g3.x, g3.y);   // RZ q0
    rz_f(p10, p11, g4.x, g4.y);   // RZ q3
    rz_f(p20, p21, g5.x, g5.y);   // RZ q6
  }

  // expand to 8 amplitudes  u[r] = p0(r&1) * p1(bit1) * p2(bit2)
  float re[8], im[8];
  {
    const float2 q00 = cmul(p00, p10), q01v = cmul(p01, p10);
    const float2 q10 = cmul(p00, p11), q11v = cmul(p01, p11);
    const float2 qq[4] = {q00, q01v, q10, q11v};
#pragma unroll
    for (int r = 0; r < 8; ++r) {
      const float2 u = cmul(qq[r & 3], (r & 4) ? p21 : p20);
      re[r] = u.x; im[r] = u.y;
    }
  }

  // remaining entangling part: CX ring on reg qubits + 10 param gates
  {
    const float2 g6 = gT[wv][6],  g7 = gT[wv][7],  g8 = gT[wv][8];
    const float2 g9 = gT[wv][9],  gA = gT[wv][10], gB = gT[wv][11];
    const float2 gC = gT[wv][12], gD = gT[wv][13], gE = gT[wv][14];
    const float2 gF = gT[wv][15];
    cx_rr<1, 2>(re, im);                 // CX(0,3)
    cx_rr<2, 4>(re, im);                 // CX(3,6)
    cx_rr<4, 1>(re, im);                 // CX(6,0)
    ry_r<1>(re, im, g6.x, g6.y);         // RY q0 w30
    rz_r<2>(re, im, g7.x, g7.y);         // RZ q3 w31
    crx_rr<2, 1>(re, im, g8.x, g8.y);    // CRX(3,0) w32
    crx_rr<2, 4>(re, im, g9.x, g9.y);    // CRX(3,6) w33
    ry_r<1>(re, im, gA.x, gA.y);         // RY q0 (w34+w36 folded)
    ry_r<4>(re, im, gB.x, gB.y);         // RY q6 (w35+w37 folded)
    cx_rr<1, 4>(re, im);                 // CX(0,6)
    rz_r<1>(re, im, gC.x, gC.y);         // RZ q0 w38
    rz_r<4>(re, im, gD.x, gD.y);         // RZ q6 w39
    crx_rr<4, 1>(re, im, gE.x, gE.y);    // CRX(6,0) w40
    ry_r<1>(re, im, gF.x, gF.y);         // RY q0 w41
  }

  // <X>,<Y>,<Z> on qubit 0 (reg bit 0); ez = 2*P(even)-1
  float zr = 0.f, zi = 0.f, pe = 0.f;
#pragma unroll
  for (int r0 = 0; r0 < 8; r0 += 2) {
    const int r1 = r0 + 1;
    zr += re[r0] * re[r1] + im[r0] * im[r1];
    zi += re[r0] * im[r1] - im[r0] * re[r1];
    pe += re[r0] * re[r0] + im[r0] * im[r0];
  }
#pragma unroll
  for (int m = 1; m < 64; m <<= 1) { zr += shx(zr, m); zi += shx(zi, m); pe += shx(pe, m); }

  if (lane == 0) {
    feats[p * 3u + 0u] = 2.0f * zr;
    feats[p * 3u + 1u] = 2.0f * zi;
    feats[p * 3u + 2u] = 2.0f * pe - 1.0f;
  }

  // ---- epilogue: last block computes the FC (release/acquire via fence+atomic) ----
  __threadfence();                  // make this block's feats stores visible
  __syncthreads();                  // all 4 waves' stores + fences done
  __shared__ unsigned int lastFlag;
  if (tid == 0) lastFlag = (atomicAdd(counter, 1u) == (unsigned)(nblk - 1)) ? 1u : 0u;
  __syncthreads();
  if (lastFlag) {
    __threadfence();                // acquire: invalidate caches before reading feats
    const int q0 = wv * 20;
    for (int q = q0; q < q0 + 20; ++q) {
      const int bb = q / 10, cc = q - 10 * bb;
      const float* f = feats + bb * 2028;
      const float* wr = fc_w + cc * 2028;
      float acc = 0.0f;
      for (int k = lane; k < 2028; k += 64) acc += f[k] * wr[k];
#pragma unroll
      for (int m = 1; m < 64; m <<= 1) acc += shx(acc, m);
      if (lane == 0) out[bb * 10 + cc] = acc + fc_b[cc];
    }
  }
}

extern "C" void kernel_launch(void* const* d_in, const int* in_sizes, int n_in,
                              void* d_out, int out_size, void* d_ws, size_t ws_size,
                              hipStream_t stream) {
  const float* x    = (const float*)d_in[0];   // (B,1,28,28)
  const float* w    = (const float*)d_in[1];   // (42,)
  const float* fc_w = (const float*)d_in[2];   // (10, 2028)
  const float* fc_b = (const float*)d_in[3];   // (10,)
  float* out = (float*)d_out;                  // (B, 10)

  const int B = in_sizes[0] / 784;             // 8
  const int npatch = B * 676;                  // 5408; divisible by 4
  const int nblk = npatch / 4;                 // 1352

  float* feats = (float*)d_ws;                             // npatch*3 floats
  unsigned int* counter = (unsigned int*)((char*)d_ws + (1 << 20)); // 1 MiB offset

  hipMemsetAsync(counter, 0, sizeof(unsigned int), stream);  // graph-legal node
  qcnn_all<<<nblk, 256, 0, stream>>>(x, w, fc_w, fc_b, feats, counter, out, nblk);
}

// Round 8
// 69.086 us; speedup vs baseline: 3.8923x; 3.8923x over previous
//
#include <hip/hip_runtime.h>

// One wavefront = one 9-qubit patch circuit; zero block-level barriers
// (per-wave LDS tables, wave-internal DS ordering). Two-kernel structure:
// feats -> d_ws, then a tiny FC kernel.
//
// R7 lesson (268us disaster): per-block __threadfence + grid-wide
// last-block-done serializes L2 writebacks across 8 XCDs — a second launch
// is ~100x cheaper than grid-scope fencing. R2: no per-patch atomics.
// R4: 1 patch/wave (TLP > ILP). The 256MB d_ws poison fill (~40us) is fixed.
//
// Qubit -> bit remap:
//   qubit 0 -> reg bit 0 (R0)  qubit 3 -> reg bit 1 (R1)  qubit 6 -> reg bit 2 (R2)
//   qubit 1 -> lane bit 0      qubit 2 -> lane bit 1      qubit 4 -> lane bit 2
//   qubit 5 -> lane bit 3      qubit 7 -> lane bit 4      qubit 8 -> lane bit 5
//
// Algebraic pipeline (all pieces correctness-proven in R6/R7):
//   enc RY + conv1 RY -> per-qubit (c,s); conv1 RZ folds into tau_q(b)
//   ring CNOT eliminated analytically (GF(2)-linear) -> per-lane product state
//   pool1 -> per-lane RX on each 2-vector factor (LUT by 2 lane bits)
//   conv2 single-qubit layer at factor level; RY(w34)RY(w36), RY(w35)RY(w37) folded
// * NEW: CX(0,3),CX(3,6),CX(6,0) folded into expansion indexing:
//     v(b0,b1,b2) = p0(b0^b2) * p1(b0^b1^b2) * p2(b1^b2)   (zero instructions)
//   then 8 param gates + CX(0,6); measure qubit0, ez = 2*P(even)-1.

__device__ __forceinline__ float shx(float v, int m) { return __shfl_xor(v, m, 64); }

__device__ __forceinline__ float2 cmul(float2 a, float2 b) {
  return make_float2(a.x * b.x - a.y * b.y, a.x * b.y + a.y * b.x);
}

// ---- full-state reg-qubit gates ----
template <int TM> __device__ __forceinline__
void ry_r(float (&re)[8], float (&im)[8], float c, float s) {
#pragma unroll
  for (int r0 = 0; r0 < 8; ++r0) if (!(r0 & TM)) {
    const int r1 = r0 | TM;
    float a = re[r0], bb = re[r1];
    re[r0] = c * a - s * bb; re[r1] = s * a + c * bb;
    a = im[r0]; bb = im[r1];
    im[r0] = c * a - s * bb; im[r1] = s * a + c * bb;
  }
}
template <int TM> __device__ __forceinline__
void rz_r(float (&re)[8], float (&im)[8], float c, float s) {
#pragma unroll
  for (int r = 0; r < 8; ++r) {
    const float sg = (r & TM) ? s : -s;
    const float a = re[r], bb = im[r];
    re[r] = c * a - sg * bb;
    im[r] = c * bb + sg * a;
  }
}
template <int CM, int TM> __device__ __forceinline__
void cx_rr(float (&re)[8], float (&im)[8]) {
#pragma unroll
  for (int r0 = 0; r0 < 8; ++r0) if ((r0 & CM) && !(r0 & TM)) {
    const int r1 = r0 | TM;
    float t = re[r0]; re[r0] = re[r1]; re[r1] = t;
    t = im[r0]; im[r0] = im[r1]; im[r1] = t;
  }
}
template <int CM, int TM> __device__ __forceinline__
void crx_rr(float (&re)[8], float (&im)[8], float co, float si) {
#pragma unroll
  for (int r0 = 0; r0 < 8; ++r0) if ((r0 & CM) && !(r0 & TM)) {
    const int r1 = r0 | TM;
    const float r0r = re[r0], r0i = im[r0], r1r = re[r1], r1i = im[r1];
    re[r0] = co * r0r + si * r1i; im[r0] = co * r0i - si * r1r;
    re[r1] = co * r1r + si * r0i; im[r1] = co * r1i - si * r0r;
  }
}

// ---- factor-level single-qubit gates on a complex 2-vector (A,B) ----
__device__ __forceinline__
void ry_f(float2& A, float2& B, float c, float s) {
  const float2 nA = make_float2(c * A.x - s * B.x, c * A.y - s * B.y);
  const float2 nB = make_float2(s * A.x + c * B.x, s * A.y + c * B.y);
  A = nA; B = nB;
}
__device__ __forceinline__
void rz_f(float2& A, float2& B, float c, float s) {
  A = make_float2(c * A.x + s * A.y, c * A.y - s * A.x);   // * e^{-i t/2}
  B = make_float2(c * B.x - s * B.y, c * B.y + s * B.x);   // * e^{+i t/2}
}
__device__ __forceinline__
void rx_f(float2& A, float2& B, float c, float s) {         // pool1 folded RX
  const float2 nA = make_float2(c * A.x + s * B.y, c * A.y - s * B.x);
  const float2 nB = make_float2(c * B.x + s * A.y, c * B.y - s * A.x);
  A = nA; B = nB;
}

__global__ __launch_bounds__(256) void qcnn_fused(const float* __restrict__ x,
                                                  const float* __restrict__ w,
                                                  float* __restrict__ feats) {
  // per-wave LDS regions — no cross-wave sharing, no barriers
  __shared__ float4 tauT[4][9];    // qubit q -> (t0r, t0i, t1r, t1i)
  __shared__ float2 rxT[4][12];    // pool1 RX LUT [axis][2 control bits]
  __shared__ float2 gT[4][16];     // folded gate params (cos, sin)

  const int tid = threadIdx.x;
  const int wv = tid >> 6, lane = tid & 63;
  const unsigned p = blockIdx.x * 4u + wv;           // patch id (grid exact)
  const unsigned b = p / 676u;
  const unsigned rem = p - b * 676u;
  const unsigned i = rem / 26u, j = rem - i * 26u;

  // ---- per-wave table build (lane roles; same-wave DS ordering) ----
  if (lane < 9) {
    const int di = lane / 3, dj = lane - di * 3;
    const float xv = x[b * 784u + (i + di) * 28u + (j + dj)];
    const float ang = fmaf(xv, 3.14159265358979323846f, w[lane]) * 0.5f;
    float s, c; __sincosf(ang, &s, &c);
    float zs, zc; __sincosf(0.5f * w[9 + lane], &zs, &zc);
    tauT[wv][lane] = make_float4(c * zc, -c * zs, s * zc, s * zs);
  } else if (lane < 21) {
    const int k = lane - 9, a = k >> 2, cb = k & 3;
    float th = 0.0f;
    if (cb & 1) th += w[18 + 2 * a];
    if (cb & 2) th += w[19 + 2 * a];
    float s, c; __sincosf(0.5f * th, &s, &c);
    rxT[wv][k] = make_float2(c, s);
  } else if (lane < 37) {
    const int k = lane - 21;
    float th;
    if (k < 10)       th = w[24 + k];            // w24..w33
    else if (k == 10) th = w[34] + w[36];        // folded RY q0
    else if (k == 11) th = w[35] + w[37];        // folded RY q6
    else              th = w[26 + k];            // w38..w41
    float s, c; __sincosf(0.5f * th, &s, &c);
    gT[wv][k] = make_float2(c, s);
  }

  const int l0 = lane & 1, l1 = (lane >> 1) & 1, l2 = (lane >> 2) & 1;
  const int l3 = (lane >> 3) & 1, l4 = (lane >> 4) & 1, l5 = (lane >> 5) & 1;

  float4 tq[9];
#pragma unroll
  for (int q = 0; q < 9; ++q) tq[q] = tauT[wv][q];
  auto tau = [&](int bit, int q) -> float2 {
    const float4 t = tq[q];
    return bit ? make_float2(t.z, t.w) : make_float2(t.x, t.y);
  };

  // post-ring product-state factors (derivation verified R6/R7)
  const int a0 = l5, a1 = l0 ^ l5;
  float2 p00 = cmul(tau(a0, 0), tau(a1, 1));
  float2 p01 = cmul(tau(a0 ^ 1, 0), tau(a1 ^ 1, 1));
  float2 p10 = cmul(tau(l1, 3), tau(l2, 4));
  float2 p11 = cmul(tau(l1 ^ 1, 3), tau(l2 ^ 1, 4));
  float2 p20 = cmul(tau(l3, 6), tau(l4, 7));
  float2 p21 = cmul(tau(l3 ^ 1, 6), tau(l4 ^ 1, 7));
  const float2 T = cmul(cmul(tau(l0 ^ l1, 2), tau(l2 ^ l3, 5)), tau(l4 ^ l5, 8));
  p20 = cmul(p20, T);
  p21 = cmul(p21, T);

  // pool1: per-lane RX on each factor
  {
    const float2 x0 = rxT[wv][lane & 3];
    const float2 x1 = rxT[wv][4 + ((lane >> 2) & 3)];
    const float2 x2 = rxT[wv][8 + ((lane >> 4) & 3)];
    rx_f(p00, p01, x0.x, x0.y);
    rx_f(p10, p11, x1.x, x1.y);
    rx_f(p20, p21, x2.x, x2.y);
  }

  // conv2 single-qubit layer at FACTOR level (w24..w29)
  {
    const float2 g0 = gT[wv][0], g1 = gT[wv][1], g2 = gT[wv][2];
    const float2 g3 = gT[wv][3], g4 = gT[wv][4], g5 = gT[wv][5];
    ry_f(p00, p01, g0.x, g0.y);   // RY q0
    ry_f(p10, p11, g1.x, g1.y);   // RY q3
    ry_f(p20, p21, g2.x, g2.y);   // RY q6
    rz_f(p00, p01, g3.x, g3.y);   // RZ q0
    rz_f(p10, p11, g4.x, g4.y);   // RZ q3
    rz_f(p20, p21, g5.x, g5.y);   // RZ q6
  }

  // expand with CX(0,3),CX(3,6),CX(6,0) FOLDED into the index map:
  //   v(b0,b1,b2) = p0(b0^b2) * p1(b0^b1^b2) * p2(b1^b2)
  float re[8], im[8];
  {
    const float2 q00 = cmul(p00, p10);   // p0(0)p1(0)
    const float2 q01 = cmul(p00, p11);   // p0(0)p1(1)
    const float2 q10 = cmul(p01, p10);   // p0(1)p1(0)
    const float2 q11 = cmul(p01, p11);   // p0(1)p1(1)
    float2 u;
    u = cmul(q00, p20); re[0] = u.x; im[0] = u.y;   // r=0: p0(0)p1(0)p2(0)
    u = cmul(q11, p20); re[1] = u.x; im[1] = u.y;   // r=1: p0(1)p1(1)p2(0)
    u = cmul(q01, p21); re[2] = u.x; im[2] = u.y;   // r=2: p0(0)p1(1)p2(1)
    u = cmul(q10, p21); re[3] = u.x; im[3] = u.y;   // r=3: p0(1)p1(0)p2(1)
    u = cmul(q11, p21); re[4] = u.x; im[4] = u.y;   // r=4: p0(1)p1(1)p2(1)
    u = cmul(q00, p21); re[5] = u.x; im[5] = u.y;   // r=5: p0(0)p1(0)p2(1)
    u = cmul(q10, p20); re[6] = u.x; im[6] = u.y;   // r=6: p0(1)p1(0)p2(0)
    u = cmul(q01, p20); re[7] = u.x; im[7] = u.y;   // r=7: p0(0)p1(1)p2(0)
  }

  // remaining gates (post-CX-trio): 8 parametrized + CX(0,6)
  {
    const float2 g6 = gT[wv][6],  g7 = gT[wv][7],  g8 = gT[wv][8];
    const float2 g9 = gT[wv][9],  gA = gT[wv][10], gB = gT[wv][11];
    const float2 gC = gT[wv][12], gD = gT[wv][13], gE = gT[wv][14];
    const float2 gF = gT[wv][15];
    ry_r<1>(re, im, g6.x, g6.y);         // RY q0 w30
    rz_r<2>(re, im, g7.x, g7.y);         // RZ q3 w31
    crx_rr<2, 1>(re, im, g8.x, g8.y);    // CRX(3,0) w32
    crx_rr<2, 4>(re, im, g9.x, g9.y);    // CRX(3,6) w33
    ry_r<1>(re, im, gA.x, gA.y);         // RY q0 (w34+w36)
    ry_r<4>(re, im, gB.x, gB.y);         // RY q6 (w35+w37)
    cx_rr<1, 4>(re, im);                 // CX(0,6)
    rz_r<1>(re, im, gC.x, gC.y);         // RZ q0 w38
    rz_r<4>(re, im, gD.x, gD.y);         // RZ q6 w39
    crx_rr<4, 1>(re, im, gE.x, gE.y);    // CRX(6,0) w40
    ry_r<1>(re, im, gF.x, gF.y);         // RY q0 w41
  }

  // <X>,<Y>,<Z> on qubit 0 (reg bit 0); ez = 2*P(even)-1
  float zr = 0.f, zi = 0.f, pe = 0.f;
#pragma unroll
  for (int r0 = 0; r0 < 8; r0 += 2) {
    const int r1 = r0 + 1;
    zr += re[r0] * re[r1] + im[r0] * im[r1];
    zi += re[r0] * im[r1] - im[r0] * re[r1];
    pe += re[r0] * re[r0] + im[r0] * im[r0];
  }
#pragma unroll
  for (int m = 1; m < 64; m <<= 1) { zr += shx(zr, m); zi += shx(zi, m); pe += shx(pe, m); }

  if (lane == 0) {
    feats[p * 3u + 0u] = 2.0f * zr;
    feats[p * 3u + 1u] = 2.0f * zi;
    feats[p * 3u + 2u] = 2.0f * pe - 1.0f;
  }
}

// out[b,c] = fc_b[c] + dot(feats[b,:], fc_w[c,:]) over 2028 elements.
__global__ __launch_bounds__(256) void fc_kernel(const float* __restrict__ feats,
                                                 const float* __restrict__ fc_w,
                                                 const float* __restrict__ fc_b,
                                                 float* __restrict__ out) {
  const int b = blockIdx.x / 10, c = blockIdx.x - b * 10;
  const float* f = feats + b * 2028;
  const float* wr = fc_w + c * 2028;
  float acc = 0.0f;
  for (int k = threadIdx.x; k < 2028; k += 256) acc += f[k] * wr[k];
#pragma unroll
  for (int m = 1; m < 64; m <<= 1) acc += __shfl_xor(acc, m, 64);
  __shared__ float sbuf[4];
  const int lane = threadIdx.x & 63, wv = threadIdx.x >> 6;
  if (lane == 0) sbuf[wv] = acc;
  __syncthreads();
  if (threadIdx.x == 0) out[b * 10 + c] = sbuf[0] + sbuf[1] + sbuf[2] + sbuf[3] + fc_b[c];
}

extern "C" void kernel_launch(void* const* d_in, const int* in_sizes, int n_in,
                              void* d_out, int out_size, void* d_ws, size_t ws_size,
                              hipStream_t stream) {
  const float* x    = (const float*)d_in[0];   // (B,1,28,28)
  const float* w    = (const float*)d_in[1];   // (42,)
  const float* fc_w = (const float*)d_in[2];   // (10, 2028)
  const float* fc_b = (const float*)d_in[3];   // (10,)
  float* out = (float*)d_out;                  // (B, 10)

  const int B = in_sizes[0] / 784;             // 8
  const int npatch = B * 676;                  // 5408; divisible by 4

  float* feats = (float*)d_ws;                 // npatch*3 floats, fully written

  qcnn_fused<<<npatch / 4, 256, 0, stream>>>(x, w, feats);
  fc_kernel<<<B * 10, 256, 0, stream>>>(feats, fc_w, fc_b, out);
}